// Round 6
// baseline (191.391 us; speedup 1.0000x reference)
//
#include <hip/hip_runtime.h>

#define NQ 16384
#define NV 16384
#define DMODEL 256

typedef __bf16 bf16x8 __attribute__((ext_vector_type(8)));
typedef float f32x4 __attribute__((ext_vector_type(4)));

__device__ __forceinline__ unsigned short f2bf(float x) {
    union { float f; unsigned int u; } v; v.f = x;
    unsigned int r = v.u + 0x7fff + ((v.u >> 16) & 1);
    return (unsigned short)(r >> 16);
}
__device__ __forceinline__ float blo(unsigned int u) {
    union { unsigned int u; float f; } v; v.u = u << 16; return v.f;
}
__device__ __forceinline__ float bhi(unsigned int u) {
    union { unsigned int u; float f; } v; v.u = u & 0xFFFF0000u; return v.f;
}
__device__ __forceinline__ f32x4 mfma16(bf16x8 a, bf16x8 b, f32x4 c) {
    return __builtin_amdgcn_mfma_f32_16x16x32_bf16(a, b, c, 0, 0, 0);
}

// ---------------- prep (blocks 0..607) + pipelined streaming LN (blocks 608..1631) ----------------
// LN: 1024 blocks x 128 rows, 4 chunks of 32 rows, double-buffered loads so the
// next chunk's 8 float4 loads are in flight while the current chunk reduces.
__global__ __launch_bounds__(256) void k_prep_ln(
    const float* __restrict__ Wv, const float* __restrict__ Woff,
    const float* __restrict__ Wattn, const float* __restrict__ Wout,
    unsigned short* __restrict__ WtV, unsigned short* __restrict__ WtC,
    unsigned short* __restrict__ WtO,
    const float* __restrict__ feat, const float* __restrict__ query,
    const float* __restrict__ fns, const float* __restrict__ fnb,
    const float* __restrict__ qns, const float* __restrict__ qnb,
    unsigned short* __restrict__ lnf, unsigned short* __restrict__ lnq) {
    if (blockIdx.x < 608) {
        int t = blockIdx.x * 256 + threadIdx.x;
        if (t < 256 * 256) { int n = t >> 8, k = t & 255; WtV[t] = f2bf(Wv[k * 256 + n]); return; }
        t -= 256 * 256;
        if (t < 256 * 256) { int n = t >> 8, k = t & 255; WtO[t] = f2bf(Wout[k * 256 + n]); return; }
        t -= 256 * 256;
        if (t < 96 * 256) {
            int j = t >> 8, k = t & 255;
            float w = (j < 64) ? Woff[k * 64 + j] : Wattn[k * 32 + (j - 64)];
            WtC[j * 256 + k] = f2bf(w);
        }
        return;
    }
    const int lb = blockIdx.x - 608;
    const float* src; const float* scale; const float* bias; unsigned short* dst;
    int row0;
    if (lb < 512) { src = feat;  scale = fns; bias = fnb; dst = lnf; row0 = lb * 128; }
    else          { src = query; scale = qns; bias = qnb; dst = lnq; row0 = (lb - 512) * 128; }
    const int lane = threadIdx.x & 63;
    const int w = threadIdx.x >> 6;
    const int g = lane >> 4, li = lane & 15;
    float4 sc[4], bi[4];
#pragma unroll
    for (int j = 0; j < 4; ++j) {
        sc[j] = *(const float4*)(scale + li * 16 + j * 4);
        bi[j] = *(const float4*)(bias + li * 16 + j * 4);
    }
    const int rbase = row0 + w * 8 + g;

    float4 xa[2][4], xb[2][4];
#define LN_LOAD(buf, coff)                                                            \
    _Pragma("unroll") for (int h2 = 0; h2 < 2; ++h2)                                  \
        _Pragma("unroll") for (int j = 0; j < 4; ++j)                                 \
            buf[h2][j] = *(const float4*)(src + (size_t)(rbase + (coff) + h2 * 4) * 256 + li * 16 + j * 4);
#define LN_PROC(buf, coff)                                                            \
    _Pragma("unroll") for (int h2 = 0; h2 < 2; ++h2) {                                \
        float s = 0.f, sq = 0.f;                                                      \
        _Pragma("unroll") for (int j = 0; j < 4; ++j) {                               \
            s  += buf[h2][j].x + buf[h2][j].y + buf[h2][j].z + buf[h2][j].w;          \
            sq += buf[h2][j].x * buf[h2][j].x + buf[h2][j].y * buf[h2][j].y +         \
                  buf[h2][j].z * buf[h2][j].z + buf[h2][j].w * buf[h2][j].w;          \
        }                                                                             \
        _Pragma("unroll") for (int d = 1; d < 16; d <<= 1) {                          \
            s  += __shfl_xor(s, d);                                                   \
            sq += __shfl_xor(sq, d);                                                  \
        }                                                                             \
        float mu = s * 0.00390625f;                                                   \
        float rstd = rsqrtf(sq * 0.00390625f - mu * mu + 1e-6f);                      \
        unsigned int pk[8];                                                           \
        _Pragma("unroll") for (int j = 0; j < 4; ++j) {                               \
            pk[2 * j] = (unsigned)f2bf((buf[h2][j].x - mu) * rstd * sc[j].x + bi[j].x) |      \
                        ((unsigned)f2bf((buf[h2][j].y - mu) * rstd * sc[j].y + bi[j].y) << 16); \
            pk[2 * j + 1] = (unsigned)f2bf((buf[h2][j].z - mu) * rstd * sc[j].z + bi[j].z) |   \
                            ((unsigned)f2bf((buf[h2][j].w - mu) * rstd * sc[j].w + bi[j].w) << 16); \
        }                                                                             \
        uint4* dstp = (uint4*)(dst + (size_t)(rbase + (coff) + h2 * 4) * 256 + li * 16); \
        dstp[0] = make_uint4(pk[0], pk[1], pk[2], pk[3]);                             \
        dstp[1] = make_uint4(pk[4], pk[5], pk[6], pk[7]);                             \
    }
    LN_LOAD(xa, 0)
    LN_LOAD(xb, 32)
    LN_PROC(xa, 0)
    LN_LOAD(xa, 64)
    LN_PROC(xb, 32)
    LN_LOAD(xb, 96)
    LN_PROC(xa, 64)
    LN_PROC(xb, 96)
}

#define STAGE_A(srcbuf)                                                               \
    {                                                                                 \
        const int c = threadIdx.x & 31;                                               \
        const int rt = threadIdx.x >> 5;                                              \
        _Pragma("unroll") for (int i = 0; i < 16; ++i) {                              \
            const int r = rt + i * 8;                                                 \
            *(uint4*)&A[r * 264 + c * 8] =                                            \
                *(const uint4*)((srcbuf) + (size_t)(m0 + r) * 256 + c * 8);           \
        }                                                                             \
    }

#define MFMA_STEP_V(bf, kk)                                                           \
    _Pragma("unroll") for (int m = 0; m < 8; ++m) {                                   \
        bf16x8 a = *(const bf16x8*)&A[(m * 16 + lrow) * 264 + (kk) * 32 + lk];        \
        _Pragma("unroll") for (int i = 0; i < 4; ++i)                                 \
            acc[i][m] = mfma16(bf[i], a, acc[i][m]);                                  \
    }

// ---------------- value GEMM: lnf @ WtV^T + b_value -> bf16 value ----------------
__global__ __launch_bounds__(256) void k_value(
    const unsigned short* __restrict__ lnf, const float* __restrict__ b_value,
    const unsigned short* __restrict__ WtV, unsigned short* __restrict__ value) {
    __shared__ unsigned short A[128 * 264];
    const int m0 = blockIdx.x * 128;
    STAGE_A(lnf)
    __syncthreads();
    const int lane = threadIdx.x & 63;
    const int w = threadIdx.x >> 6;
    const int lrow = lane & 15, lk = (lane >> 4) * 8;
    f32x4 acc[4][8];
#pragma unroll
    for (int i = 0; i < 4; ++i)
#pragma unroll
        for (int m = 0; m < 8; ++m) acc[i][m] = (f32x4){0.f, 0.f, 0.f, 0.f};
#define LOADB_V(dst, kk)                                                              \
    _Pragma("unroll") for (int i = 0; i < 4; ++i) dst[i] =                            \
        *(const bf16x8*)(WtV + (size_t)((w * 4 + i) * 16 + lrow) * 256 + (kk) * 32 + lk);
    {
        bf16x8 b0[4], b1[4];
        LOADB_V(b0, 0)
#pragma unroll
        for (int k2 = 0; k2 < 4; ++k2) {
            LOADB_V(b1, k2 * 2 + 1)
            MFMA_STEP_V(b0, k2 * 2)
            if (k2 < 3) { LOADB_V(b0, k2 * 2 + 2) }
            MFMA_STEP_V(b1, k2 * 2 + 1)
        }
    }
    __syncthreads();   // all LDS reads of A done; reuse A as bf16 D-tile
    const int g = lane >> 4;
#pragma unroll
    for (int i = 0; i < 4; ++i) {
        const int col0 = (w * 4 + i) * 16 + g * 4;
        float4 bv = *(const float4*)(b_value + col0);
#pragma unroll
        for (int m = 0; m < 8; ++m) {
            uint2 r;
            r.x = (unsigned)f2bf(acc[i][m][0] + bv.x) | ((unsigned)f2bf(acc[i][m][1] + bv.y) << 16);
            r.y = (unsigned)f2bf(acc[i][m][2] + bv.z) | ((unsigned)f2bf(acc[i][m][3] + bv.w) << 16);
            *(uint2*)&A[(m * 16 + (lane & 15)) * 264 + col0] = r;
        }
    }
    __syncthreads();
    {
        const int c = threadIdx.x & 31;
        const int rt = threadIdx.x >> 5;
#pragma unroll
        for (int i = 0; i < 16; ++i) {
            const int r = rt + i * 8;
            *(uint4*)(value + (size_t)(m0 + r) * 256 + c * 8) = *(uint4*)&A[r * 264 + c * 8];
        }
    }
}

// ---------------- qoff GEMM + softmax -> samples ----------------
__global__ __launch_bounds__(256) void k_qoff(
    const unsigned short* __restrict__ lnq, const float* __restrict__ refpt,
    const float* __restrict__ b_off, const float* __restrict__ b_attn,
    const unsigned short* __restrict__ WtC, float4* __restrict__ samples) {
    __shared__ unsigned short A[128 * 264];
    const int m0 = blockIdx.x * 128;
    STAGE_A(lnq)
    __syncthreads();
    const int lane = threadIdx.x & 63;
    const int w = threadIdx.x >> 6;
    const int lrow = lane & 15, lk = (lane >> 4) * 8;
    f32x4 acc[6][2];
#pragma unroll
    for (int i = 0; i < 6; ++i)
#pragma unroll
        for (int m = 0; m < 2; ++m) acc[i][m] = (f32x4){0.f, 0.f, 0.f, 0.f};
#define LOADB_Q(dst, kk)                                                              \
    _Pragma("unroll") for (int i = 0; i < 6; ++i) dst[i] =                            \
        *(const bf16x8*)(WtC + (size_t)(i * 16 + lrow) * 256 + (kk) * 32 + lk);
#define MFMA_STEP_Q(bf, kk)                                                           \
    _Pragma("unroll") for (int m = 0; m < 2; ++m) {                                   \
        bf16x8 a = *(const bf16x8*)&A[(w * 32 + m * 16 + lrow) * 264 + (kk) * 32 + lk]; \
        _Pragma("unroll") for (int i = 0; i < 6; ++i)                                 \
            acc[i][m] = mfma16(bf[i], a, acc[i][m]);                                  \
    }
    {
        bf16x8 b0[6], b1[6];
        LOADB_Q(b0, 0)
#pragma unroll
        for (int k2 = 0; k2 < 4; ++k2) {
            LOADB_Q(b1, k2 * 2 + 1)
            MFMA_STEP_Q(b0, k2 * 2)
            if (k2 < 3) { LOADB_Q(b0, k2 * 2 + 2) }
            MFMA_STEP_Q(b1, k2 * 2 + 1)
        }
    }
    __syncthreads();
    // per-wave D buffer in A's region: 32 rows x 96 cols fp32, stride 100
    float* Dl = (float*)A + w * 4224;
#pragma unroll
    for (int i = 0; i < 6; ++i) {
        const int col0 = i * 16 + (lane >> 4) * 4;
#pragma unroll
        for (int m = 0; m < 2; ++m) {
            const int rl = m * 16 + (lane & 15);
            *(float4*)&Dl[rl * 100 + col0] =
                make_float4(acc[i][m][0], acc[i][m][1], acc[i][m][2], acc[i][m][3]);
        }
    }
    __syncthreads();
#pragma unroll
    for (int it = 0; it < 4; ++it) {
        int idx = it * 64 + lane;     // 32 rows x 8 heads
        int rl = idx >> 3;
        int h = idx & 7;
        int row = m0 + w * 32 + rl;
        float rx = refpt[(size_t)row * 2 + 0] * 128.f - 0.5f;
        float ry = refpt[(size_t)row * 2 + 1] * 128.f - 0.5f;
        float l0 = Dl[rl * 100 + 64 + h * 4 + 0] + b_attn[h * 4 + 0];
        float l1 = Dl[rl * 100 + 64 + h * 4 + 1] + b_attn[h * 4 + 1];
        float l2 = Dl[rl * 100 + 64 + h * 4 + 2] + b_attn[h * 4 + 2];
        float l3 = Dl[rl * 100 + 64 + h * 4 + 3] + b_attn[h * 4 + 3];
        float mx = fmaxf(fmaxf(l0, l1), fmaxf(l2, l3));
        float e0 = __expf(l0 - mx), e1 = __expf(l1 - mx);
        float e2 = __expf(l2 - mx), e3 = __expf(l3 - mx);
        float inv = 1.f / (e0 + e1 + e2 + e3);
        float ww[4] = {e0 * inv, e1 * inv, e2 * inv, e3 * inv};
#pragma unroll
        for (int p = 0; p < 4; ++p) {
            float ox = Dl[rl * 100 + h * 8 + p * 2 + 0] + b_off[h * 8 + p * 2 + 0];
            float oy = Dl[rl * 100 + h * 8 + p * 2 + 1] + b_off[h * 8 + p * 2 + 1];
            samples[((size_t)row * 8 + h) * 4 + p] = make_float4(rx + ox, ry + oy, ww[p], 0.f);
        }
    }
}

// ---------------- bilinear gather + attention-weighted sum -> bf16 acc ----------------
__global__ __launch_bounds__(256) void k_gather(
    const unsigned short* __restrict__ value, const float4* __restrict__ samples,
    unsigned short* __restrict__ accb) {
    const int tid = blockIdx.x * 256 + threadIdx.x;
    const int sub = tid & 3;         // channel-quad (8 channels)
    const int t = tid >> 2;          // (b*NQ+q)*8 + h
    const int h = t & 7;
    const int bq = t >> 3;
    const int b = bq >> 14;
    const unsigned short* vb = value + ((size_t)b << 14) * 256 + h * 32 + sub * 8;
    float a0 = 0.f, a1 = 0.f, a2 = 0.f, a3 = 0.f;
    float a4 = 0.f, a5 = 0.f, a6 = 0.f, a7 = 0.f;
#pragma unroll
    for (int p = 0; p < 4; ++p) {
        float4 s = samples[(size_t)t * 4 + p];
        float xf = floorf(s.x), yf = floorf(s.y);
        float fx = s.x - xf, fy = s.y - yf;
        int x0 = (int)xf, y0 = (int)yf;
        int x1 = x0 + 1, y1 = y0 + 1;
        float wgt = s.z;
        bool bx0 = (unsigned)x0 < 128u, bx1 = (unsigned)x1 < 128u;
        bool by0 = (unsigned)y0 < 128u, by1 = (unsigned)y1 < 128u;
        float wt[4];
        wt[0] = (bx0 && by0) ? (1.f - fx) * (1.f - fy) * wgt : 0.f;
        wt[1] = (bx1 && by0) ? fx * (1.f - fy) * wgt : 0.f;
        wt[2] = (bx0 && by1) ? (1.f - fx) * fy * wgt : 0.f;
        wt[3] = (bx1 && by1) ? fx * fy * wgt : 0.f;
        int xc0 = min(max(x0, 0), 127), xc1 = min(max(x1, 0), 127);
        int yc0 = min(max(y0, 0), 127), yc1 = min(max(y1, 0), 127);
        int pix[4];
        pix[0] = yc0 * 128 + xc0; pix[1] = yc0 * 128 + xc1;
        pix[2] = yc1 * 128 + xc0; pix[3] = yc1 * 128 + xc1;
#pragma unroll
        for (int tp = 0; tp < 4; ++tp) {
            uint4 u = *(const uint4*)(vb + (size_t)pix[tp] * 256);
            float w = wt[tp];
            a0 = fmaf(w, blo(u.x), a0); a1 = fmaf(w, bhi(u.x), a1);
            a2 = fmaf(w, blo(u.y), a2); a3 = fmaf(w, bhi(u.y), a3);
            a4 = fmaf(w, blo(u.z), a4); a5 = fmaf(w, bhi(u.z), a5);
            a6 = fmaf(w, blo(u.w), a6); a7 = fmaf(w, bhi(u.w), a7);
        }
    }
    uint4 r;
    r.x = (unsigned)f2bf(a0) | ((unsigned)f2bf(a1) << 16);
    r.y = (unsigned)f2bf(a2) | ((unsigned)f2bf(a3) << 16);
    r.z = (unsigned)f2bf(a4) | ((unsigned)f2bf(a5) << 16);
    r.w = (unsigned)f2bf(a6) | ((unsigned)f2bf(a7) << 16);
    *(uint4*)(accb + (size_t)bq * 256 + h * 32 + sub * 8) = r;
}

// ---------------- out GEMM + bias + gated residual ----------------
__global__ __launch_bounds__(256) void k_out(
    const unsigned short* __restrict__ accb, const unsigned short* __restrict__ WtO,
    const float* __restrict__ b_out, const float* __restrict__ gamma,
    const float* __restrict__ query, float* __restrict__ out) {
    __shared__ unsigned short A[128 * 264];
    const int m0 = blockIdx.x * 128;
    STAGE_A(accb)
    __syncthreads();
    const int lane = threadIdx.x & 63;
    const int w = threadIdx.x >> 6;
    const int lrow = lane & 15, lk = (lane >> 4) * 8;
    f32x4 acc[4][8];
#pragma unroll
    for (int i = 0; i < 4; ++i)
#pragma unroll
        for (int m = 0; m < 8; ++m) acc[i][m] = (f32x4){0.f, 0.f, 0.f, 0.f};
#define LOADB_O(dst, kk)                                                              \
    _Pragma("unroll") for (int i = 0; i < 4; ++i) dst[i] =                            \
        *(const bf16x8*)(WtO + (size_t)((w * 4 + i) * 16 + lrow) * 256 + (kk) * 32 + lk);
    {
        bf16x8 b0[4], b1[4];
        LOADB_O(b0, 0)
#pragma unroll
        for (int k2 = 0; k2 < 4; ++k2) {
            LOADB_O(b1, k2 * 2 + 1)
            MFMA_STEP_V(b0, k2 * 2)
            if (k2 < 3) { LOADB_O(b0, k2 * 2 + 2) }
            MFMA_STEP_V(b1, k2 * 2 + 1)
        }
    }
    const int g = lane >> 4;
    float4 bo[4], gm[4];
#pragma unroll
    for (int i = 0; i < 4; ++i) {
        bo[i] = *(const float4*)(b_out + (w * 4 + i) * 16 + g * 4);
        gm[i] = *(const float4*)(gamma + (w * 4 + i) * 16 + g * 4);
    }
#pragma unroll
    for (int m = 0; m < 8; ++m) {
        const size_t row = (size_t)(m0 + m * 16 + (lane & 15));
#pragma unroll
        for (int i = 0; i < 4; ++i) {
            const int col0 = (w * 4 + i) * 16 + g * 4;
            float4 q = *(const float4*)(query + row * 256 + col0);
            float4 o;
            o.x = q.x + gm[i].x * (acc[i][m][0] + bo[i].x);
            o.y = q.y + gm[i].y * (acc[i][m][1] + bo[i].y);
            o.z = q.z + gm[i].z * (acc[i][m][2] + bo[i].z);
            o.w = q.w + gm[i].w * (acc[i][m][3] + bo[i].w);
            *(float4*)(out + row * 256 + col0) = o;
        }
    }
}

extern "C" void kernel_launch(void* const* d_in, const int* in_sizes, int n_in,
                              void* d_out, int out_size, void* d_ws, size_t ws_size,
                              hipStream_t stream) {
    const float* query    = (const float*)d_in[0];
    const float* feat     = (const float*)d_in[1];
    const float* refpt    = (const float*)d_in[2];
    const float* qn_scale = (const float*)d_in[5];
    const float* qn_bias  = (const float*)d_in[6];
    const float* fn_scale = (const float*)d_in[7];
    const float* fn_bias  = (const float*)d_in[8];
    const float* W_value  = (const float*)d_in[9];
    const float* b_value  = (const float*)d_in[10];
    const float* W_off    = (const float*)d_in[11];
    const float* b_off    = (const float*)d_in[12];
    const float* W_attn   = (const float*)d_in[13];
    const float* b_attn   = (const float*)d_in[14];
    const float* W_out    = (const float*)d_in[15];
    const float* b_out    = (const float*)d_in[16];
    const float* gamma    = (const float*)d_in[17];
    float* out = (float*)d_out;

    char* ws = (char*)d_ws;
    unsigned short* WtV   = (unsigned short*)(ws);
    unsigned short* WtO   = (unsigned short*)(ws + 131072);
    unsigned short* WtC   = (unsigned short*)(ws + 262144);
    unsigned short* value = (unsigned short*)(ws + 311296);
    // region A: lnf, later overwritten by samples (stream-ordered)
    char* regA = ws + 311296 + 33554432;
    // region B: lnq, later overwritten by accb (stream-ordered)
    char* regB = ws + 311296 + 2 * 33554432;
    unsigned short* lnf     = (unsigned short*)regA;
    float4*         samples = (float4*)regA;
    unsigned short* lnq     = (unsigned short*)regB;
    unsigned short* accb    = (unsigned short*)regB;

    hipLaunchKernelGGL(k_prep_ln, dim3(1632), dim3(256), 0, stream,
                       W_value, W_off, W_attn, W_out, WtV, WtC, WtO,
                       feat, query, fn_scale, fn_bias, qn_scale, qn_bias, lnf, lnq);
    hipLaunchKernelGGL(k_value, dim3(512), dim3(256), 0, stream,
                       lnf, b_value, WtV, value);
    hipLaunchKernelGGL(k_qoff, dim3(512), dim3(256), 0, stream,
                       lnq, refpt, b_off, b_attn, WtC, samples);
    hipLaunchKernelGGL(k_gather, dim3(8192), dim3(256), 0, stream,
                       value, samples, accb);
    hipLaunchKernelGGL(k_out, dim3(512), dim3(256), 0, stream,
                       accb, WtO, b_out, gamma, query, out);
}

// Round 7
// 175.623 us; speedup vs baseline: 1.0898x; 1.0898x over previous
//
#include <hip/hip_runtime.h>

#define NQ 16384
#define NV 16384
#define DMODEL 256

typedef __bf16 bf16x8 __attribute__((ext_vector_type(8)));
typedef float f32x4 __attribute__((ext_vector_type(4)));

__device__ __forceinline__ unsigned short f2bf(float x) {
    union { float f; unsigned int u; } v; v.f = x;
    unsigned int r = v.u + 0x7fff + ((v.u >> 16) & 1);
    return (unsigned short)(r >> 16);
}
__device__ __forceinline__ float blo(unsigned int u) {
    union { unsigned int u; float f; } v; v.u = u << 16; return v.f;
}
__device__ __forceinline__ float bhi(unsigned int u) {
    union { unsigned int u; float f; } v; v.u = u & 0xFFFF0000u; return v.f;
}
__device__ __forceinline__ f32x4 mfma16(bf16x8 a, bf16x8 b, f32x4 c) {
    return __builtin_amdgcn_mfma_f32_16x16x32_bf16(a, b, c, 0, 0, 0);
}

// ---------------- prep: scaled transposed weights + LN-fold constants ----------------
// WtV[n][k] = fns[k]*Wv[k][n]; WtC[j][k] = qns[k]*Wc[k][j]; WtO[n][k] = Wout[k][n]
// csumV[n] = sum_k fns[k]*Wv[k][n]; preV[n] = sum_k fnb[k]*Wv[k][n] + b_value[n]
// csumC[j] = sum_k qns[k]*Wc[k][j]; preC[j] = sum_k qnb[k]*Wc[k][j] + (b_off||b_attn)[j]
__global__ __launch_bounds__(256) void k_prep(
    const float* __restrict__ Wv, const float* __restrict__ Woff,
    const float* __restrict__ Wattn, const float* __restrict__ Wout,
    const float* __restrict__ fns, const float* __restrict__ fnb,
    const float* __restrict__ qns, const float* __restrict__ qnb,
    const float* __restrict__ b_value, const float* __restrict__ b_off,
    const float* __restrict__ b_attn,
    unsigned short* __restrict__ WtV, unsigned short* __restrict__ WtC,
    unsigned short* __restrict__ WtO,
    float* __restrict__ csumV, float* __restrict__ preV,
    float* __restrict__ csumC, float* __restrict__ preC) {
    const int blk = blockIdx.x;
    if (blk < 608) {
        int t = blk * 256 + threadIdx.x;
        if (t < 65536) { int n = t >> 8, k = t & 255; WtV[t] = f2bf(fns[k] * Wv[k * 256 + n]); return; }
        t -= 65536;
        if (t < 65536) { int n = t >> 8, k = t & 255; WtO[t] = f2bf(Wout[k * 256 + n]); return; }
        t -= 65536;
        if (t < 24576) {
            int j = t >> 8, k = t & 255;
            float w = (j < 64) ? Woff[k * 64 + j] : Wattn[k * 32 + (j - 64)];
            WtC[j * 256 + k] = f2bf(qns[k] * w);
        }
        return;
    }
    if (blk < 612) {   // csumV / preV, 64 columns per block, 4 k-parts
        __shared__ float sCS[4][64], sPR[4][64];
        const int nl = threadIdx.x & 63;
        const int n = (blk - 608) * 64 + nl;
        const int kp = threadIdx.x >> 6;
        float cs = 0.f, pr = 0.f;
        for (int k = kp * 64; k < kp * 64 + 64; ++k) {
            float w = Wv[k * 256 + n];
            cs += fns[k] * w;
            pr += fnb[k] * w;
        }
        sCS[kp][nl] = cs; sPR[kp][nl] = pr;
        __syncthreads();
        if (threadIdx.x < 64) {
            int nn = (blk - 608) * 64 + threadIdx.x;
            csumV[nn] = sCS[0][threadIdx.x] + sCS[1][threadIdx.x] + sCS[2][threadIdx.x] + sCS[3][threadIdx.x];
            preV[nn] = sPR[0][threadIdx.x] + sPR[1][threadIdx.x] + sPR[2][threadIdx.x] + sPR[3][threadIdx.x]
                       + b_value[nn];
        }
        return;
    }
    {   // blk == 612: csumC / preC (96 outputs, 2 k-parts)
        __shared__ float sCS[2][96], sPR[2][96];
        const int t = threadIdx.x;
        if (t < 192) {
            const int n = t % 96;
            const int kp = t / 96;
            float cs = 0.f, pr = 0.f;
            for (int k = kp * 128; k < kp * 128 + 128; ++k) {
                float w = (n < 64) ? Woff[k * 64 + n] : Wattn[k * 32 + (n - 64)];
                cs += qns[k] * w;
                pr += qnb[k] * w;
            }
            sCS[kp][n] = cs; sPR[kp][n] = pr;
        }
        __syncthreads();
        if (t < 96) {
            csumC[t] = sCS[0][t] + sCS[1][t];
            preC[t] = sPR[0][t] + sPR[1][t] + ((t < 64) ? b_off[t] : b_attn[t - 64]);
        }
        return;
    }
}

// stage raw fp32 -> bf16 LDS tile + per-row stats (2 threads/row, fp32 sums)
#define STAGE_RAW(srcptr)                                                             \
    {                                                                                 \
        const int t = threadIdx.x;                                                    \
        const int r = t >> 1, h = t & 1;                                              \
        const float* src = (srcptr) + (size_t)(m0 + r) * 256 + h * 128;               \
        unsigned short* dstp = &A[r * 264 + h * 128];                                 \
        float s = 0.f, sq = 0.f;                                                      \
        _Pragma("unroll 8") for (int j = 0; j < 32; ++j) {                            \
            float4 x = *(const float4*)(src + j * 4);                                 \
            s += x.x + x.y + x.z + x.w;                                               \
            sq += x.x * x.x + x.y * x.y + x.z * x.z + x.w * x.w;                      \
            uint2 pk;                                                                 \
            pk.x = (unsigned)f2bf(x.x) | ((unsigned)f2bf(x.y) << 16);                 \
            pk.y = (unsigned)f2bf(x.z) | ((unsigned)f2bf(x.w) << 16);                 \
            *(uint2*)(dstp + j * 4) = pk;                                             \
        }                                                                             \
        s += __shfl_xor(s, 1);                                                        \
        sq += __shfl_xor(sq, 1);                                                      \
        if (h == 0) {                                                                 \
            float mu = s * 0.00390625f;                                               \
            muL[r] = mu;                                                              \
            rsL[r] = rsqrtf(sq * 0.00390625f - mu * mu + 1e-6f);                      \
        }                                                                             \
    }

#define STAGE_A(srcbuf)                                                               \
    {                                                                                 \
        const int c = threadIdx.x & 31;                                               \
        const int rt = threadIdx.x >> 5;                                              \
        _Pragma("unroll") for (int i = 0; i < 16; ++i) {                              \
            const int r = rt + i * 8;                                                 \
            *(uint4*)&A[r * 264 + c * 8] =                                            \
                *(const uint4*)((srcbuf) + (size_t)(m0 + r) * 256 + c * 8);           \
        }                                                                             \
    }

#define MFMA_STEP_V(bf, kk)                                                           \
    _Pragma("unroll") for (int m = 0; m < 8; ++m) {                                   \
        bf16x8 a = *(const bf16x8*)&A[(m * 16 + lrow) * 264 + (kk) * 32 + lk];        \
        _Pragma("unroll") for (int i = 0; i < 4; ++i)                                 \
            acc[i][m] = mfma16(bf[i], a, acc[i][m]);                                  \
    }

// ---------------- value GEMM on raw feat with LN folded into epilogue ----------------
__global__ __launch_bounds__(256) void k_value(
    const float* __restrict__ feat, const float* __restrict__ csumV,
    const float* __restrict__ preV, const unsigned short* __restrict__ WtV,
    unsigned short* __restrict__ value) {
    __shared__ unsigned short A[128 * 264];
    __shared__ float muL[128], rsL[128];
    const int m0 = blockIdx.x * 128;
    STAGE_RAW(feat)
    __syncthreads();
    const int lane = threadIdx.x & 63;
    const int w = threadIdx.x >> 6;
    const int lrow = lane & 15, lk = (lane >> 4) * 8;
    f32x4 acc[4][8];
#pragma unroll
    for (int i = 0; i < 4; ++i)
#pragma unroll
        for (int m = 0; m < 8; ++m) acc[i][m] = (f32x4){0.f, 0.f, 0.f, 0.f};
#define LOADB_V(dst, kk)                                                              \
    _Pragma("unroll") for (int i = 0; i < 4; ++i) dst[i] =                            \
        *(const bf16x8*)(WtV + (size_t)((w * 4 + i) * 16 + lrow) * 256 + (kk) * 32 + lk);
    {
        bf16x8 b0[4], b1[4];
        LOADB_V(b0, 0)
#pragma unroll
        for (int k2 = 0; k2 < 4; ++k2) {
            LOADB_V(b1, k2 * 2 + 1)
            MFMA_STEP_V(b0, k2 * 2)
            if (k2 < 3) { LOADB_V(b0, k2 * 2 + 2) }
            MFMA_STEP_V(b1, k2 * 2 + 1)
        }
    }
    __syncthreads();   // A reads done; reuse A as bf16 D-tile
    const int g = lane >> 4;
#pragma unroll
    for (int i = 0; i < 4; ++i) {
        const int col0 = (w * 4 + i) * 16 + g * 4;
        float4 cs = *(const float4*)(csumV + col0);
        float4 pr = *(const float4*)(preV + col0);
#pragma unroll
        for (int m = 0; m < 8; ++m) {
            const int rl = m * 16 + (lane & 15);
            float mu = muL[rl], rs = rsL[rl];
            uint2 r;
            r.x = (unsigned)f2bf(rs * (acc[i][m][0] - mu * cs.x) + pr.x) |
                  ((unsigned)f2bf(rs * (acc[i][m][1] - mu * cs.y) + pr.y) << 16);
            r.y = (unsigned)f2bf(rs * (acc[i][m][2] - mu * cs.z) + pr.z) |
                  ((unsigned)f2bf(rs * (acc[i][m][3] - mu * cs.w) + pr.w) << 16);
            *(uint2*)&A[rl * 264 + col0] = r;
        }
    }
    __syncthreads();
    {
        const int c = threadIdx.x & 31;
        const int rt = threadIdx.x >> 5;
#pragma unroll
        for (int i = 0; i < 16; ++i) {
            const int r = rt + i * 8;
            *(uint4*)(value + (size_t)(m0 + r) * 256 + c * 8) = *(uint4*)&A[r * 264 + c * 8];
        }
    }
}

// ---------------- qoff GEMM on raw query + LN-fold + softmax -> samples ----------------
__global__ __launch_bounds__(256) void k_qoff(
    const float* __restrict__ query, const float* __restrict__ refpt,
    const float* __restrict__ csumC, const float* __restrict__ preC,
    const unsigned short* __restrict__ WtC, float4* __restrict__ samples) {
    __shared__ unsigned short A[128 * 264];
    __shared__ float muL[128], rsL[128];
    const int m0 = blockIdx.x * 128;
    STAGE_RAW(query)
    __syncthreads();
    const int lane = threadIdx.x & 63;
    const int w = threadIdx.x >> 6;
    const int lrow = lane & 15, lk = (lane >> 4) * 8;
    f32x4 acc[6][2];
#pragma unroll
    for (int i = 0; i < 6; ++i)
#pragma unroll
        for (int m = 0; m < 2; ++m) acc[i][m] = (f32x4){0.f, 0.f, 0.f, 0.f};
#define LOADB_Q(dst, kk)                                                              \
    _Pragma("unroll") for (int i = 0; i < 6; ++i) dst[i] =                            \
        *(const bf16x8*)(WtC + (size_t)(i * 16 + lrow) * 256 + (kk) * 32 + lk);
#define MFMA_STEP_Q(bf, kk)                                                           \
    _Pragma("unroll") for (int m = 0; m < 2; ++m) {                                   \
        bf16x8 a = *(const bf16x8*)&A[(w * 32 + m * 16 + lrow) * 264 + (kk) * 32 + lk]; \
        _Pragma("unroll") for (int i = 0; i < 6; ++i)                                 \
            acc[i][m] = mfma16(bf[i], a, acc[i][m]);                                  \
    }
    {
        bf16x8 b0[6], b1[6];
        LOADB_Q(b0, 0)
#pragma unroll
        for (int k2 = 0; k2 < 4; ++k2) {
            LOADB_Q(b1, k2 * 2 + 1)
            MFMA_STEP_Q(b0, k2 * 2)
            if (k2 < 3) { LOADB_Q(b0, k2 * 2 + 2) }
            MFMA_STEP_Q(b1, k2 * 2 + 1)
        }
    }
    __syncthreads();
    // per-wave D buffer in A's region: 32 rows x 96 cols fp32, stride 100
    float* Dl = (float*)A + w * 4224;
#pragma unroll
    for (int i = 0; i < 6; ++i) {
        const int col0 = i * 16 + (lane >> 4) * 4;
#pragma unroll
        for (int m = 0; m < 2; ++m) {
            const int rl = m * 16 + (lane & 15);
            *(float4*)&Dl[rl * 100 + col0] =
                make_float4(acc[i][m][0], acc[i][m][1], acc[i][m][2], acc[i][m][3]);
        }
    }
    __syncthreads();
#pragma unroll
    for (int it = 0; it < 4; ++it) {
        int idx = it * 64 + lane;     // 32 rows x 8 heads
        int rl = idx >> 3;
        int h = idx & 7;
        int row = m0 + w * 32 + rl;
        float mu = muL[w * 32 + rl], rs = rsL[w * 32 + rl];
        float rx = refpt[(size_t)row * 2 + 0] * 128.f - 0.5f;
        float ry = refpt[(size_t)row * 2 + 1] * 128.f - 0.5f;
        float l0 = rs * (Dl[rl * 100 + 64 + h * 4 + 0] - mu * csumC[64 + h * 4 + 0]) + preC[64 + h * 4 + 0];
        float l1 = rs * (Dl[rl * 100 + 64 + h * 4 + 1] - mu * csumC[64 + h * 4 + 1]) + preC[64 + h * 4 + 1];
        float l2 = rs * (Dl[rl * 100 + 64 + h * 4 + 2] - mu * csumC[64 + h * 4 + 2]) + preC[64 + h * 4 + 2];
        float l3 = rs * (Dl[rl * 100 + 64 + h * 4 + 3] - mu * csumC[64 + h * 4 + 3]) + preC[64 + h * 4 + 3];
        float mx = fmaxf(fmaxf(l0, l1), fmaxf(l2, l3));
        float e0 = __expf(l0 - mx), e1 = __expf(l1 - mx);
        float e2 = __expf(l2 - mx), e3 = __expf(l3 - mx);
        float inv = 1.f / (e0 + e1 + e2 + e3);
        float ww[4] = {e0 * inv, e1 * inv, e2 * inv, e3 * inv};
#pragma unroll
        for (int p = 0; p < 4; ++p) {
            float ox = rs * (Dl[rl * 100 + h * 8 + p * 2 + 0] - mu * csumC[h * 8 + p * 2 + 0]) + preC[h * 8 + p * 2 + 0];
            float oy = rs * (Dl[rl * 100 + h * 8 + p * 2 + 1] - mu * csumC[h * 8 + p * 2 + 1]) + preC[h * 8 + p * 2 + 1];
            samples[((size_t)row * 8 + h) * 4 + p] = make_float4(rx + ox, ry + oy, ww[p], 0.f);
        }
    }
}

// ---------------- bilinear gather + attention-weighted sum -> bf16 acc ----------------
__global__ __launch_bounds__(256) void k_gather(
    const unsigned short* __restrict__ value, const float4* __restrict__ samples,
    unsigned short* __restrict__ accb) {
    const int tid = blockIdx.x * 256 + threadIdx.x;
    const int sub = tid & 3;         // channel-quad (8 channels)
    const int t = tid >> 2;          // (b*NQ+q)*8 + h
    const int h = t & 7;
    const int bq = t >> 3;
    const int b = bq >> 14;
    const unsigned short* vb = value + ((size_t)b << 14) * 256 + h * 32 + sub * 8;
    float a0 = 0.f, a1 = 0.f, a2 = 0.f, a3 = 0.f;
    float a4 = 0.f, a5 = 0.f, a6 = 0.f, a7 = 0.f;
#pragma unroll
    for (int p = 0; p < 4; ++p) {
        float4 s = samples[(size_t)t * 4 + p];
        float xf = floorf(s.x), yf = floorf(s.y);
        float fx = s.x - xf, fy = s.y - yf;
        int x0 = (int)xf, y0 = (int)yf;
        int x1 = x0 + 1, y1 = y0 + 1;
        float wgt = s.z;
        bool bx0 = (unsigned)x0 < 128u, bx1 = (unsigned)x1 < 128u;
        bool by0 = (unsigned)y0 < 128u, by1 = (unsigned)y1 < 128u;
        float wt[4];
        wt[0] = (bx0 && by0) ? (1.f - fx) * (1.f - fy) * wgt : 0.f;
        wt[1] = (bx1 && by0) ? fx * (1.f - fy) * wgt : 0.f;
        wt[2] = (bx0 && by1) ? (1.f - fx) * fy * wgt : 0.f;
        wt[3] = (bx1 && by1) ? fx * fy * wgt : 0.f;
        int xc0 = min(max(x0, 0), 127), xc1 = min(max(x1, 0), 127);
        int yc0 = min(max(y0, 0), 127), yc1 = min(max(y1, 0), 127);
        int pix[4];
        pix[0] = yc0 * 128 + xc0; pix[1] = yc0 * 128 + xc1;
        pix[2] = yc1 * 128 + xc0; pix[3] = yc1 * 128 + xc1;
#pragma unroll
        for (int tp = 0; tp < 4; ++tp) {
            uint4 u = *(const uint4*)(vb + (size_t)pix[tp] * 256);
            float w = wt[tp];
            a0 = fmaf(w, blo(u.x), a0); a1 = fmaf(w, bhi(u.x), a1);
            a2 = fmaf(w, blo(u.y), a2); a3 = fmaf(w, bhi(u.y), a3);
            a4 = fmaf(w, blo(u.z), a4); a5 = fmaf(w, bhi(u.z), a5);
            a6 = fmaf(w, blo(u.w), a6); a7 = fmaf(w, bhi(u.w), a7);
        }
    }
    uint4 r;
    r.x = (unsigned)f2bf(a0) | ((unsigned)f2bf(a1) << 16);
    r.y = (unsigned)f2bf(a2) | ((unsigned)f2bf(a3) << 16);
    r.z = (unsigned)f2bf(a4) | ((unsigned)f2bf(a5) << 16);
    r.w = (unsigned)f2bf(a6) | ((unsigned)f2bf(a7) << 16);
    *(uint4*)(accb + (size_t)bq * 256 + h * 32 + sub * 8) = r;
}

// ---------------- out GEMM + bias + gated residual ----------------
__global__ __launch_bounds__(256) void k_out(
    const unsigned short* __restrict__ accb, const unsigned short* __restrict__ WtO,
    const float* __restrict__ b_out, const float* __restrict__ gamma,
    const float* __restrict__ query, float* __restrict__ out) {
    __shared__ unsigned short A[128 * 264];
    const int m0 = blockIdx.x * 128;
    STAGE_A(accb)
    __syncthreads();
    const int lane = threadIdx.x & 63;
    const int w = threadIdx.x >> 6;
    const int lrow = lane & 15, lk = (lane >> 4) * 8;
    f32x4 acc[4][8];
#pragma unroll
    for (int i = 0; i < 4; ++i)
#pragma unroll
        for (int m = 0; m < 8; ++m) acc[i][m] = (f32x4){0.f, 0.f, 0.f, 0.f};
#define LOADB_O(dst, kk)                                                              \
    _Pragma("unroll") for (int i = 0; i < 4; ++i) dst[i] =                            \
        *(const bf16x8*)(WtO + (size_t)((w * 4 + i) * 16 + lrow) * 256 + (kk) * 32 + lk);
    {
        bf16x8 b0[4], b1[4];
        LOADB_O(b0, 0)
#pragma unroll
        for (int k2 = 0; k2 < 4; ++k2) {
            LOADB_O(b1, k2 * 2 + 1)
            MFMA_STEP_V(b0, k2 * 2)
            if (k2 < 3) { LOADB_O(b0, k2 * 2 + 2) }
            MFMA_STEP_V(b1, k2 * 2 + 1)
        }
    }
    const int g = lane >> 4;
    float4 bo[4], gm[4];
#pragma unroll
    for (int i = 0; i < 4; ++i) {
        bo[i] = *(const float4*)(b_out + (w * 4 + i) * 16 + g * 4);
        gm[i] = *(const float4*)(gamma + (w * 4 + i) * 16 + g * 4);
    }
#pragma unroll
    for (int m = 0; m < 8; ++m) {
        const size_t row = (size_t)(m0 + m * 16 + (lane & 15));
#pragma unroll
        for (int i = 0; i < 4; ++i) {
            const int col0 = (w * 4 + i) * 16 + g * 4;
            float4 q = *(const float4*)(query + row * 256 + col0);
            float4 o;
            o.x = q.x + gm[i].x * (acc[i][m][0] + bo[i].x);
            o.y = q.y + gm[i].y * (acc[i][m][1] + bo[i].y);
            o.z = q.z + gm[i].z * (acc[i][m][2] + bo[i].z);
            o.w = q.w + gm[i].w * (acc[i][m][3] + bo[i].w);
            *(float4*)(out + row * 256 + col0) = o;
        }
    }
}

extern "C" void kernel_launch(void* const* d_in, const int* in_sizes, int n_in,
                              void* d_out, int out_size, void* d_ws, size_t ws_size,
                              hipStream_t stream) {
    const float* query    = (const float*)d_in[0];
    const float* feat     = (const float*)d_in[1];
    const float* refpt    = (const float*)d_in[2];
    const float* qn_scale = (const float*)d_in[5];
    const float* qn_bias  = (const float*)d_in[6];
    const float* fn_scale = (const float*)d_in[7];
    const float* fn_bias  = (const float*)d_in[8];
    const float* W_value  = (const float*)d_in[9];
    const float* b_value  = (const float*)d_in[10];
    const float* W_off    = (const float*)d_in[11];
    const float* b_off    = (const float*)d_in[12];
    const float* W_attn   = (const float*)d_in[13];
    const float* b_attn   = (const float*)d_in[14];
    const float* W_out    = (const float*)d_in[15];
    const float* b_out    = (const float*)d_in[16];
    const float* gamma    = (const float*)d_in[17];
    float* out = (float*)d_out;

    char* ws = (char*)d_ws;
    unsigned short* WtV   = (unsigned short*)(ws);            // 128 KB
    unsigned short* WtO   = (unsigned short*)(ws + 131072);   // 128 KB
    unsigned short* WtC   = (unsigned short*)(ws + 262144);   // 48 KB -> ends 311296
    float* csumV = (float*)(ws + 311296);                     // 1 KB
    float* preV  = (float*)(ws + 312320);                     // 1 KB
    float* csumC = (float*)(ws + 313344);                     // 512 B
    float* preC  = (float*)(ws + 313856);                     // 512 B -> ends 314368
    unsigned short* value = (unsigned short*)(ws + 315392);   // 32 MB
    float4* samples       = (float4*)(ws + 315392 + 33554432);
    unsigned short* accb  = (unsigned short*)(ws + 315392 + 2 * 33554432);

    hipLaunchKernelGGL(k_prep, dim3(613), dim3(256), 0, stream,
                       W_value, W_off, W_attn, W_out,
                       fn_scale, fn_bias, qn_scale, qn_bias,
                       b_value, b_off, b_attn,
                       WtV, WtC, WtO, csumV, preV, csumC, preC);
    hipLaunchKernelGGL(k_value, dim3(512), dim3(256), 0, stream,
                       feat, csumV, preV, WtV, value);
    hipLaunchKernelGGL(k_qoff, dim3(512), dim3(256), 0, stream,
                       query, refpt, csumC, preC, WtC, samples);
    hipLaunchKernelGGL(k_gather, dim3(8192), dim3(256), 0, stream,
                       value, samples, accb);
    hipLaunchKernelGGL(k_out, dim3(512), dim3(256), 0, stream,
                       accb, WtO, b_out, gamma, query, out);
}